// Round 6
// baseline (100.360 us; speedup 1.0000x reference)
//
#include <hip/hip_runtime.h>
#include <math.h>

#define N_SAMP 32768
#define K_COMP 2048
#define ZD 64
#define LNC 191.896324792608546f   // 64*(0.5*log(2pi) + 0.5*log(64))
#define LN2F 0.69314718055994531f
#define INV_LN2 1.44269504088896340f
// w = dot*(1/(64 ln2)) + ck2 ; wlp_nat = w*ln2 + bias_nat
#define S2C 0.02254211001388974f   // 1/(64*ln2)

#define TILES_TOT 128              // K_COMP/16
#define TPS 4                      // tiles per stage (= waves per block)
#define STAGES (TILES_TOT / TPS)   // 32 stages

typedef __attribute__((ext_vector_type(8))) short short8;
typedef __attribute__((ext_vector_type(4))) float v4f;

#if __has_builtin(__builtin_amdgcn_exp2f)
#define EXP2(x) __builtin_amdgcn_exp2f(x)
#else
#define EXP2(x) exp2f(x)
#endif

typedef const __attribute__((address_space(1))) unsigned int* gas_t;
typedef __attribute__((address_space(3))) unsigned int* las_t;
// async global->LDS DMA, 16 B/lane: LDS dst = lp + lane*16 (wave-uniform lp)
__device__ inline void gload_lds16(const void* g, void* l) {
    __builtin_amdgcn_global_load_lds((gas_t)g, (las_t)l, 16, 0, 0);
}

__device__ inline unsigned short f2bf(float f) {
    unsigned int u = __float_as_uint(f);
    u += 0x7fffu + ((u >> 16) & 1u);  // RNE
    return (unsigned short)(u >> 16);
}
__device__ inline float bf2f(unsigned short h) {
    return __uint_as_float(((unsigned int)h) << 16);
}

// ---------------------------------------------------------------------------
// prep: blocks 0..31 build fragment-linearized locs hi/lo (lf) + ck2.
//       block 32 computes lse = logsumexp(logits) concurrently.
// lf layout: tile T (16 comps) -> 4 KB: 4 regions {hi d0-31, hi d32-63,
// lo d0-31, lo d32-63} x 64 lanes x 16 B == mix's A-fragment order.
// ---------------------------------------------------------------------------
__global__ __launch_bounds__(256) void prep_kernel(
    const float* __restrict__ locs, const float* __restrict__ logits,
    float* __restrict__ ck2, float* __restrict__ lse_out,
    char* __restrict__ lf) {
    if (blockIdx.x < 32) {
        int gid = blockIdx.x * 256 + threadIdx.x;   // 0..8191
        int T = gid >> 6;
        int l = gid & 63;
        int n = l & 15, q = l >> 4;
        int k = T * 16 + n;

        const float* src = locs + (size_t)k * ZD + q * 8;
        float4 u0 = *(const float4*)(src);
        float4 u1 = *(const float4*)(src + 4);
        float4 u2 = *(const float4*)(src + 32);
        float4 u3 = *(const float4*)(src + 36);
        float a[8] = {u0.x, u0.y, u0.z, u0.w, u1.x, u1.y, u1.z, u1.w};
        float b[8] = {u2.x, u2.y, u2.z, u2.w, u3.x, u3.y, u3.z, u3.w};

        short8 h0, h1, l0, l1;
        float sq = 0.f;
#pragma unroll
        for (int j = 0; j < 8; ++j) {
            unsigned short ha = f2bf(a[j]);
            h0[j] = (short)ha; l0[j] = (short)f2bf(a[j] - bf2f(ha));
            unsigned short hb = f2bf(b[j]);
            h1[j] = (short)hb; l1[j] = (short)f2bf(b[j] - bf2f(hb));
            sq = fmaf(a[j], a[j], sq);
            sq = fmaf(b[j], b[j], sq);
        }
        char* dst = lf + (size_t)T * 4096 + l * 16;
        *(short8*)(dst)        = h0;
        *(short8*)(dst + 1024) = h1;
        *(short8*)(dst + 2048) = l0;
        *(short8*)(dst + 3072) = l1;

        sq += __shfl_xor(sq, 16);
        sq += __shfl_xor(sq, 32);
        if (q == 0) ck2[k] = (logits[k] - sq * (1.0f / 128.0f)) * INV_LN2;
    } else {
        __shared__ float red[4];
        int tid = threadIdx.x;
        int wv = tid >> 6, ln = tid & 63;
        float lm = -INFINITY;
        for (int i = tid; i < K_COMP; i += 256) lm = fmaxf(lm, logits[i]);
#pragma unroll
        for (int d = 1; d < 64; d <<= 1) lm = fmaxf(lm, __shfl_xor(lm, d));
        if (ln == 0) red[wv] = lm;
        __syncthreads();
        float M = fmaxf(fmaxf(red[0], red[1]), fmaxf(red[2], red[3]));
        float ls = 0.f;
        for (int i = tid; i < K_COMP; i += 256) ls += __expf(logits[i] - M);
#pragma unroll
        for (int d = 1; d < 64; d <<= 1) ls += __shfl_xor(ls, d);
        __syncthreads();
        if (ln == 0) red[wv] = ls;
        __syncthreads();
        if (tid == 0) *lse_out = M + __logf(red[0] + red[1] + red[2] + red[3]);
    }
}

// ---------------------------------------------------------------------------
// mix: block = 256 thr = 4 waves, SAMPLE-split (wave w owns samples
// w*16..w*16+15; all waves stream all 128 k-tiles). A-tiles go through
// double-buffered LDS via global_load_lds DMA (m97 pattern): stage = 4 tiles
// = 16 KB, wave w DMAs tile w (4x 1KB regions), one barrier per stage.
// Per tile: 4 ds_read_b128 + 6 chained MFMA (tiles processed in ILP pairs)
// + flat exp2-sum (w <= ~1.5 provably; no online max) + tree argmax.
// ---------------------------------------------------------------------------
__global__ __launch_bounds__(256, 2) void mix_kernel(
    const float* __restrict__ x, const float* __restrict__ locs,
    const char* __restrict__ lf, const float* __restrict__ ck2,
    const float* __restrict__ lse_ptr, float* __restrict__ out) {

    __shared__ char buf[2][TPS * 4096];   // 2 x 16 KB
    __shared__ int amax_sh[64];

    const int tid  = threadIdx.x;
    const int lane = tid & 63;
    const int wv   = __builtin_amdgcn_readfirstlane(tid >> 6);  // 0..3
    const int n    = lane & 15;
    const int quad = lane >> 4;
    const int sbase = blockIdx.x * 64;
    const int srow  = sbase + wv * 16 + n;

    // ---- B fragments (x) for this wave's 16 samples, hi/lo split; ||x||^2
    short8 bh0, bh1, bl0, bl1;
    float xs;
    {
        const float* xp = x + (size_t)srow * ZD + quad * 8;
        float4 u0 = *(const float4*)(xp);
        float4 u1 = *(const float4*)(xp + 4);
        float4 u2 = *(const float4*)(xp + 32);
        float4 u3 = *(const float4*)(xp + 36);
        float a[8] = {u0.x, u0.y, u0.z, u0.w, u1.x, u1.y, u1.z, u1.w};
        float b[8] = {u2.x, u2.y, u2.z, u2.w, u3.x, u3.y, u3.z, u3.w};
        float p = 0.f;
#pragma unroll
        for (int j = 0; j < 8; ++j) {
            unsigned short h;
            h = f2bf(a[j]); bh0[j] = (short)h; bl0[j] = (short)f2bf(a[j] - bf2f(h));
            h = f2bf(b[j]); bh1[j] = (short)h; bl1[j] = (short)f2bf(b[j] - bf2f(h));
            p = fmaf(a[j], a[j], p);
            p = fmaf(b[j], b[j], p);
        }
        p += __shfl_xor(p, 16);
        p += __shfl_xor(p, 32);
        xs = p;   // all lanes hold ||x_srow||^2 for their n
    }

    // ---- DMA helper: wave wv stages global tile (S*TPS + wv) into slot wv
    const char* gsrc0 = lf + (size_t)wv * 4096 + lane * 16;  // + S*16384 + r*1024
    char* ldst0 = &buf[0][wv * 4096];                        // + r*1024

#define DMA(S, b) do {                                                   \
    const char* _g = gsrc0 + (size_t)(S) * (TPS * 4096);                 \
    char* _l = ldst0 + (b) * (TPS * 4096);                               \
    gload_lds16(_g, _l);                                                 \
    gload_lds16(_g + 1024, _l + 1024);                                   \
    gload_lds16(_g + 2048, _l + 2048);                                   \
    gload_lds16(_g + 3072, _l + 3072);                                   \
} while (0)

    float mm = -1e30f, s0 = 0.f, s1 = 0.f;
    int ai = 0;

    // per-tile epilogue on one acc
#define EPI(acc, fcv, kb) do {                                                 \
    float w0 = fmaf((acc).x, S2C, (fcv).x);                                    \
    float w1 = fmaf((acc).y, S2C, (fcv).y);                                    \
    float w2 = fmaf((acc).z, S2C, (fcv).z);                                    \
    float w3 = fmaf((acc).w, S2C, (fcv).w);                                    \
    s0 += EXP2(w0) + EXP2(w1);                                                 \
    s1 += EXP2(w2) + EXP2(w3);                                                 \
    float t01 = fmaxf(w0, w1); int i01 = (w1 > w0) ? ((kb) + 1) : ((kb) + 0);  \
    float t23 = fmaxf(w2, w3); int i23 = (w3 > w2) ? ((kb) + 3) : ((kb) + 2);  \
    float tt2 = fmaxf(t01, t23); int it = (t23 > t01) ? i23 : i01;             \
    ai = (tt2 > mm) ? it : ai;                                                 \
    mm = fmaxf(mm, tt2);                                                       \
} while (0)

    DMA(0, 0);
    __syncthreads();   // drains vmcnt: stage 0 resident

    for (int S = 0; S < STAGES; ++S) {
        const int b = S & 1;
        if (S + 1 < STAGES) DMA(S + 1, b ^ 1);

        // ck for the 4 tiles of this stage (tiny, L2-hot)
        const float* ckS = ck2 + S * (TPS * 16) + quad * 4;
        float4 fc0 = *(const float4*)(ckS);
        float4 fc1 = *(const float4*)(ckS + 16);
        float4 fc2 = *(const float4*)(ckS + 32);
        float4 fc3 = *(const float4*)(ckS + 48);

        const char* base = &buf[b][lane * 16];
        const int kb0 = S * (TPS * 16) + quad * 4;

        // tiles in ILP pairs: two independent 6-MFMA chains
#pragma unroll
        for (int j = 0; j < TPS; j += 2) {
            const char* p0 = base + j * 4096;
            const char* p1 = base + (j + 1) * 4096;
            short8 a00 = *(const short8*)(p0);
            short8 a01 = *(const short8*)(p0 + 1024);
            short8 a02 = *(const short8*)(p0 + 2048);
            short8 a03 = *(const short8*)(p0 + 3072);
            short8 a10 = *(const short8*)(p1);
            short8 a11 = *(const short8*)(p1 + 1024);
            short8 a12 = *(const short8*)(p1 + 2048);
            short8 a13 = *(const short8*)(p1 + 3072);

            v4f ca = {0.f, 0.f, 0.f, 0.f};
            v4f cb = {0.f, 0.f, 0.f, 0.f};
            ca = __builtin_amdgcn_mfma_f32_16x16x32_bf16(a00, bh0, ca, 0, 0, 0);
            cb = __builtin_amdgcn_mfma_f32_16x16x32_bf16(a10, bh0, cb, 0, 0, 0);
            ca = __builtin_amdgcn_mfma_f32_16x16x32_bf16(a01, bh1, ca, 0, 0, 0);
            cb = __builtin_amdgcn_mfma_f32_16x16x32_bf16(a11, bh1, cb, 0, 0, 0);
            ca = __builtin_amdgcn_mfma_f32_16x16x32_bf16(a00, bl0, ca, 0, 0, 0);
            cb = __builtin_amdgcn_mfma_f32_16x16x32_bf16(a10, bl0, cb, 0, 0, 0);
            ca = __builtin_amdgcn_mfma_f32_16x16x32_bf16(a01, bl1, ca, 0, 0, 0);
            cb = __builtin_amdgcn_mfma_f32_16x16x32_bf16(a11, bl1, cb, 0, 0, 0);
            ca = __builtin_amdgcn_mfma_f32_16x16x32_bf16(a02, bh0, ca, 0, 0, 0);
            cb = __builtin_amdgcn_mfma_f32_16x16x32_bf16(a12, bh0, cb, 0, 0, 0);
            ca = __builtin_amdgcn_mfma_f32_16x16x32_bf16(a03, bh1, ca, 0, 0, 0);
            cb = __builtin_amdgcn_mfma_f32_16x16x32_bf16(a13, bh1, cb, 0, 0, 0);

            if (j == 0) { EPI(ca, fc0, kb0 + 0 * 16); EPI(cb, fc1, kb0 + 1 * 16); }
            else        { EPI(ca, fc2, kb0 + 2 * 16); EPI(cb, fc3, kb0 + 3 * 16); }
        }
        __syncthreads();  // drains DMA for S+1, protects buf[b] reuse at S+2
    }

    // ---- merge the 4 quads (disjoint comp subsets, same sample col n)
    float sum = s0 + s1;
#pragma unroll
    for (int d = 16; d <= 32; d <<= 1) {
        sum += __shfl_xor(sum, d);
        float om = __shfl_xor(mm, d);
        int   oa = __shfl_xor(ai, d);
        ai = (om > mm || (om == mm && oa < ai)) ? oa : ai;
        mm = fmaxf(mm, om);
    }

    if (quad == 0) {
        float bias = -xs * (1.0f / 128.0f) - LNC;
        out[srow] = fmaf(__log2f(sum), LN2F, bias - lse_ptr[0]);
        amax_sh[wv * 16 + n] = ai;
    }
    __syncthreads();

    // ---- quantized = locs[argmax], cooperative coalesced float4 writes
    const float4* lq = (const float4*)locs;
    float4* oq = (float4*)(out + N_SAMP + (size_t)sbase * ZD);
#pragma unroll
    for (int i = tid; i < 64 * (ZD / 4); i += 256) {
        int r = i >> 4, c = i & 15;
        oq[i] = lq[(size_t)amax_sh[r] * (ZD / 4) + c];
    }
#undef DMA
#undef EPI
}

extern "C" void kernel_launch(void* const* d_in, const int* in_sizes, int n_in,
                              void* d_out, int out_size, void* d_ws, size_t ws_size,
                              hipStream_t stream) {
    const float* x      = (const float*)d_in[0];
    const float* locs   = (const float*)d_in[1];
    const float* logits = (const float*)d_in[2];
    float* out = (float*)d_out;

    float* ck2 = (float*)d_ws;                 // 2048 floats
    float* lse = ck2 + K_COMP;                 // 1 float
    char*  lf  = (char*)d_ws + 16384;          // 512 KB fragment-linearized locs

    prep_kernel<<<33, 256, 0, stream>>>(locs, logits, ck2, lse, lf);
    mix_kernel<<<N_SAMP / 64, 256, 0, stream>>>(x, locs, lf, ck2, lse, out);
}